// Round 6
// baseline (1016.591 us; speedup 1.0000x reference)
//
#include <hip/hip_runtime.h>

#define BATCH 65536
#define TB 64

typedef _Float16 half8 __attribute__((ext_vector_type(8)));
typedef _Float16 half2v __attribute__((ext_vector_type(2)));
typedef float fx4 __attribute__((ext_vector_type(4)));

// workspace layout (halves) — total identical to R5 (zero ws-size risk)
#define PW1B_OFF 0        // [4][256][32]  W1 base rows (k<110, pad->128)
#define PW1F_OFF 32768    // [256][32]     W1 feat rows: k<15 -> feat_i, 15..29 -> feat_j
#define PW2_OFF  40960    // [8][256][32]
#define PWR_OFF  106496   // [8][256][32]
#define PWH_OFF  172032   // [8][16][32]   [mean_w | lstd_w | pad]
#define WS_TOTAL 176128

__global__ __launch_bounds__(256) void prep_weights(
    const float* __restrict__ w1, const float* __restrict__ w2,
    const float* __restrict__ wr, const float* __restrict__ wm,
    const float* __restrict__ wl, _Float16* __restrict__ ws)
{
  int idx = blockIdx.x * 256 + threadIdx.x;
  if (idx < 32768) {            // pw1b
    int kk = idx & 31, n = (idx >> 5) & 255, kt = idx >> 13;
    int k = kt * 32 + kk;
    ws[idx] = (k < 110) ? (_Float16)w1[k * 256 + n] : (_Float16)0.f;
  } else if (idx < 40960) {     // pw1f
    int t = idx - 32768;
    int kk = t & 31, n = t >> 5;
    _Float16 v = (_Float16)0.f;
    if (kk < 15)      v = (_Float16)w1[(113 + kk) * 256 + n];
    else if (kk < 30) v = (_Float16)w1[(131 + (kk - 15)) * 256 + n];
    ws[idx] = v;
  } else if (idx < 106496) {    // pw2
    int t = idx - 40960;
    int kk = t & 31, n = (t >> 5) & 255, kt = t >> 13;
    ws[idx] = (_Float16)w2[(kt * 32 + kk) * 256 + n];
  } else if (idx < 172032) {    // pwr
    int t = idx - 106496;
    int kk = t & 31, n = (t >> 5) & 255, kt = t >> 13;
    ws[idx] = (_Float16)wr[(kt * 32 + kk) * 256 + n];
  } else if (idx < WS_TOTAL) {  // pwh
    int t = idx - 172032;
    int kk = t & 31, n = (t >> 5) & 15, kt = t >> 9;
    int k = kt * 32 + kk;
    _Float16 v = (_Float16)0.f;
    if (n < 4) v = (_Float16)wm[k * 4 + n];
    else if (n < 8) v = (_Float16)wl[k * 4 + (n - 4)];
    ws[PWH_OFF + t] = v;
  }
}

// Barrier-free design (R5 post-mortem: 20 __syncthreads drains = the stall):
// each wave owns 16 batch rows and the full pipeline for them, with a
// wave-private LDS slice. LDS ops are in-order within a wave -> no
// __syncthreads anywhere. A-layout index for (row, col), K=256:
//   (((col>>5)*4 + ((col>>3)&3))*16 + row)*8 + (col&7)
// a-frag reads are lane-contiguous 1 KB ds_read_b128 -> conflict-free.
__global__ __launch_bounds__(256) void actor_fused(
    const float* __restrict__ obs, const float* __restrict__ lemb,
    const float* __restrict__ w1, const _Float16* __restrict__ ws,
    const float* __restrict__ b1, const float* __restrict__ b2,
    const float* __restrict__ br, const float* __restrict__ bm,
    const float* __restrict__ bl, float* __restrict__ out)
{
  __shared__ __align__(16) _Float16 HS[4][16 * 256];    // 32 KB: per-wave activations
  __shared__ __align__(16) _Float16 FS[4][6 * 16 * 32]; // 24 KB: per-wave feature tiles

  const _Float16* __restrict__ pw1b = ws + PW1B_OFF;
  const _Float16* __restrict__ pw1f = ws + PW1F_OFF;
  const _Float16* __restrict__ pw2  = ws + PW2_OFF;
  const _Float16* __restrict__ pwr  = ws + PWR_OFF;
  const _Float16* __restrict__ pwh  = ws + PWH_OFF;

  const int tid  = threadIdx.x;
  const int wave = tid >> 6;
  const int lane = tid & 63;
  const int q    = lane >> 4;
  const int l16  = lane & 15;
  const int rowbase = blockIdx.x * TB + wave * 16;  // this wave's 16 batch rows

  _Float16* hs = HS[wave];
  _Float16* fs = FS[wave];

  // ---- stage base (K=128: lemb 100 + body 10 + pad18) into hs, frag-major ----
  for (int idx = lane; idx < 2048; idx += 64) {
    int r = idx >> 7, c = idx & 127;
    float v = 0.f;
    if (c < 100)      v = lemb[(rowbase + r) * 100 + c];
    else if (c < 110) v = obs[(rowbase + r) * 55 + (c - 100)];
    hs[(((c >> 5) * 4 + ((c >> 3) & 3)) * 16 + r) * 8 + (c & 7)] = (_Float16)v;
  }
  // ---- stage 6 feature tiles (16 x 32 each: feat_i(15)|feat_j(15)|pad2) ----
  for (int idx = lane; idx < 3072; idx += 64) {
    int p = idx >> 9, rem = idx & 511, r = rem >> 5, c = rem & 31;
    int oi = p >> 1, oj = (1161 >> (2 * p)) & 3;
    float v = 0.f;
    if (c < 15)      v = obs[(rowbase + r) * 55 + 10 + oi * 15 + c];
    else if (c < 30) v = obs[(rowbase + r) * 55 + 10 + oj * 15 + (c - 15)];
    fs[p * 512 + ((c >> 3) * 16 + r) * 8 + (c & 7)] = (_Float16)v;
  }

  const fx4 zero4 = {0.f, 0.f, 0.f, 0.f};

  // ---- U = base @ W1base (K=128), C-layout, packed f16 (32 regs) ----
  half2v u2[32];
  {
    fx4 acc[16];
    #pragma unroll
    for (int i = 0; i < 16; ++i) acc[i] = zero4;
    for (int kt = 0; kt < 4; ++kt) {
      half8 a = *(const half8*)&hs[((kt * 4 + q) * 16 + l16) * 8];
      #pragma unroll
      for (int nt = 0; nt < 16; ++nt) {
        half8 b = *(const half8*)&pw1b[(kt * 256 + nt * 16 + l16) * 32 + q * 8];
        acc[nt] = __builtin_amdgcn_mfma_f32_16x16x32_f16(a, b, acc[nt], 0, 0, 0);
      }
    }
    #pragma unroll
    for (int nt = 0; nt < 16; ++nt)
      #pragma unroll
      for (int rp = 0; rp < 2; ++rp) {
        half2v hv;
        hv[0] = (_Float16)acc[nt][rp * 2 + 0];
        hv[1] = (_Float16)acc[nt][rp * 2 + 1];
        u2[nt * 2 + rp] = hv;
      }
  }

  half2v agg2[32];
  #pragma unroll
  for (int i = 0; i < 32; ++i) agg2[i] = (half2v)0;

  for (int p = 0; p < 6; ++p) {
    const int oi = p >> 1;
    const int oj = (1161 >> (2 * p)) & 3; // IDX_J = {1,2,0,2,0,1}
    const float* __restrict__ w1i = w1 + (110 + oi) * 256;  // one-hot i fold
    const float* __restrict__ w1j = w1 + (128 + oj) * 256;  // one-hot j fold
    half8 af = *(const half8*)&fs[p * 512 + (q * 16 + l16) * 8];

    // ---- GEMM1: h1 = relu(U + F_p @ W1f + bias_p), K=32, N in halves ----
    #pragma unroll
    for (int nh = 0; nh < 2; ++nh) {
      fx4 acc[8];
      #pragma unroll
      for (int nt = 0; nt < 8; ++nt) {
        int s = (nh * 8 + nt) * 2;
        acc[nt][0] = (float)u2[s][0];     acc[nt][1] = (float)u2[s][1];
        acc[nt][2] = (float)u2[s + 1][0]; acc[nt][3] = (float)u2[s + 1][1];
      }
      #pragma unroll
      for (int nt = 0; nt < 8; ++nt) {
        half8 b = *(const half8*)&pw1f[(nh * 128 + nt * 16 + l16) * 32 + q * 8];
        acc[nt] = __builtin_amdgcn_mfma_f32_16x16x32_f16(af, b, acc[nt], 0, 0, 0);
      }
      #pragma unroll
      for (int nt = 0; nt < 8; ++nt) {
        int col = nh * 128 + nt * 16 + l16;
        float bs = b1[col] + w1i[col] + w1j[col];
        int base = (((col >> 5) * 4 + ((col >> 3) & 3)) * 16) * 8 + (col & 7);
        #pragma unroll
        for (int rr = 0; rr < 4; ++rr) {
          float h = acc[nt][rr] + bs;
          hs[base + (q * 4 + rr) * 8] = (_Float16)(h > 0.f ? h : 0.f);
        }
      }
    }

    // ---- GEMM2: agg += relu(h1 @ W2 + b2), K=256, N in halves ----
    #pragma unroll
    for (int nh = 0; nh < 2; ++nh) {
      fx4 acc[8];
      #pragma unroll
      for (int nt = 0; nt < 8; ++nt) acc[nt] = zero4;
      for (int kt = 0; kt < 8; ++kt) {
        half8 a = *(const half8*)&hs[((kt * 4 + q) * 16 + l16) * 8];
        #pragma unroll
        for (int nt = 0; nt < 8; ++nt) {
          half8 b = *(const half8*)&pw2[(kt * 256 + nh * 128 + nt * 16 + l16) * 32 + q * 8];
          acc[nt] = __builtin_amdgcn_mfma_f32_16x16x32_f16(a, b, acc[nt], 0, 0, 0);
        }
      }
      #pragma unroll
      for (int nt = 0; nt < 8; ++nt) {
        float bs = b2[nh * 128 + nt * 16 + l16];
        #pragma unroll
        for (int rp = 0; rp < 2; ++rp) {
          float h0 = acc[nt][rp * 2 + 0] + bs;
          float h1 = acc[nt][rp * 2 + 1] + bs;
          half2v hv;
          hv[0] = (_Float16)(h0 > 0.f ? h0 : 0.f);
          hv[1] = (_Float16)(h1 > 0.f ? h1 : 0.f);
          agg2[(nh * 8 + nt) * 2 + rp] += hv;   // v_pk_add_f16
        }
      }
    }
  }

  // ---- stage agg2 -> hs (A-layout, f16) ----
  #pragma unroll
  for (int i = 0; i < 16; ++i) {
    int col = i * 16 + l16;
    int base = (((col >> 5) * 4 + ((col >> 3) & 3)) * 16) * 8 + (col & 7);
    #pragma unroll
    for (int rr = 0; rr < 4; ++rr)
      hs[base + (q * 4 + rr) * 8] = agg2[i * 2 + (rr >> 1)][rr & 1];
  }

  // ---- GEMM3: r = relu(agg @ rho + br), K=256, FULL N (all reads precede writes) ----
  {
    fx4 acc3[16];
    #pragma unroll
    for (int i = 0; i < 16; ++i) acc3[i] = zero4;
    for (int kt = 0; kt < 8; ++kt) {
      half8 a = *(const half8*)&hs[((kt * 4 + q) * 16 + l16) * 8];
      #pragma unroll
      for (int nt = 0; nt < 16; ++nt) {
        half8 b = *(const half8*)&pwr[(kt * 256 + nt * 16 + l16) * 32 + q * 8];
        acc3[nt] = __builtin_amdgcn_mfma_f32_16x16x32_f16(a, b, acc3[nt], 0, 0, 0);
      }
    }
    #pragma unroll
    for (int nt = 0; nt < 16; ++nt) {
      int col = nt * 16 + l16;
      float bs = br[col];
      int base = (((col >> 5) * 4 + ((col >> 3) & 3)) * 16) * 8 + (col & 7);
      #pragma unroll
      for (int rr = 0; rr < 4; ++rr) {
        float h = acc3[nt][rr] + bs;
        hs[base + (q * 4 + rr) * 8] = (_Float16)(h > 0.f ? h : 0.f);
      }
    }
  }

  // ---- heads: [mean | log_std] = r @ PWh (N padded to 16) ----
  fx4 a4 = zero4;
  for (int kt = 0; kt < 8; ++kt) {
    half8 a = *(const half8*)&hs[((kt * 4 + q) * 16 + l16) * 8];
    half8 b = *(const half8*)&pwh[(kt * 16 + l16) * 32 + q * 8];
    a4 = __builtin_amdgcn_mfma_f32_16x16x32_f16(a, b, a4, 0, 0, 0);
  }
  int gr = rowbase + q * 4;
  if (l16 < 4) {
    float bias = bm[l16];
    #pragma unroll
    for (int rr = 0; rr < 4; ++rr) out[(gr + rr) * 4 + l16] = a4[rr] + bias;
  } else if (l16 < 8) {
    int c = l16 - 4;
    float bias = bl[c];
    #pragma unroll
    for (int rr = 0; rr < 4; ++rr) {
      float v = a4[rr] + bias;
      v = v < -20.f ? -20.f : (v > 2.f ? 2.f : v);
      out[BATCH * 4 + (gr + rr) * 4 + c] = v;
    }
  }
}

extern "C" void kernel_launch(void* const* d_in, const int* in_sizes, int n_in,
                              void* d_out, int out_size, void* d_ws, size_t ws_size,
                              hipStream_t stream) {
  const float* obs  = (const float*)d_in[0];
  const float* lemb = (const float*)d_in[1];
  const float* w1   = (const float*)d_in[2];
  const float* b1   = (const float*)d_in[3];
  const float* w2   = (const float*)d_in[4];
  const float* b2   = (const float*)d_in[5];
  const float* wr   = (const float*)d_in[6];
  const float* br   = (const float*)d_in[7];
  const float* wm   = (const float*)d_in[8];
  const float* bm   = (const float*)d_in[9];
  const float* wl   = (const float*)d_in[10];
  const float* bl   = (const float*)d_in[11];
  float* out = (float*)d_out;
  _Float16* ws = (_Float16*)d_ws;

  hipLaunchKernelGGL(prep_weights, dim3(WS_TOTAL / 256), dim3(256), 0, stream,
                     w1, w2, wr, wm, wl, ws);
  hipLaunchKernelGGL(actor_fused, dim3(BATCH / TB), dim3(256), 0, stream,
                     obs, lemb, w1, (const _Float16*)ws, b1, b2, br, bm, bl, out);
}

// Round 7
// 301.672 us; speedup vs baseline: 3.3699x; 3.3699x over previous
//
#include <hip/hip_runtime.h>

#define BATCH 65536
#define TB 32

typedef _Float16 half8 __attribute__((ext_vector_type(8)));
typedef _Float16 half2v __attribute__((ext_vector_type(2)));
typedef float fx4 __attribute__((ext_vector_type(4)));

// workspace layout (halves)
#define PW1B_OFF 0        // [4][256][32]  W1 base rows (k<110, pad->128)
#define PW1F_OFF 32768    // [256][32]     W1 feat rows: kk<15 -> feat_i (113+kk), kk 15..29 -> feat_j (131+kk-15)
#define PW2_OFF  40960    // [8][256][32]
#define PWR_OFF  106496   // [8][256][32]
#define PWH_OFF  172032   // [8][16][32]   [mean_w | lstd_w | pad]
#define WS_TOTAL 176128

// Hs A-layout index, 32 rows x 256 cols, fragment-major
#define HIDX(row, col) (((((col) >> 5) * 4 + (((col) >> 3) & 3)) * 32 + (row)) * 8 + ((col) & 7))

__global__ __launch_bounds__(256) void prep_weights(
    const float* __restrict__ w1, const float* __restrict__ w2,
    const float* __restrict__ wr, const float* __restrict__ wm,
    const float* __restrict__ wl, _Float16* __restrict__ ws)
{
  int idx = blockIdx.x * 256 + threadIdx.x;
  if (idx < 32768) {            // pw1b
    int kk = idx & 31, n = (idx >> 5) & 255, kt = idx >> 13;
    int k = kt * 32 + kk;
    ws[idx] = (k < 110) ? (_Float16)w1[k * 256 + n] : (_Float16)0.f;
  } else if (idx < 40960) {     // pw1f
    int t = idx - 32768;
    int kk = t & 31, n = t >> 5;
    _Float16 v = (_Float16)0.f;
    if (kk < 15)      v = (_Float16)w1[(113 + kk) * 256 + n];
    else if (kk < 30) v = (_Float16)w1[(131 + (kk - 15)) * 256 + n];
    ws[idx] = v;
  } else if (idx < 106496) {    // pw2
    int t = idx - 40960;
    int kk = t & 31, n = (t >> 5) & 255, kt = t >> 13;
    ws[idx] = (_Float16)w2[(kt * 32 + kk) * 256 + n];
  } else if (idx < 172032) {    // pwr
    int t = idx - 106496;
    int kk = t & 31, n = (t >> 5) & 255, kt = t >> 13;
    ws[idx] = (_Float16)wr[(kt * 32 + kk) * 256 + n];
  } else if (idx < WS_TOTAL) {  // pwh
    int t = idx - 172032;
    int kk = t & 31, n = (t >> 5) & 15, kt = t >> 9;
    int k = kt * 32 + kk;
    _Float16 v = (_Float16)0.f;
    if (n < 4) v = (_Float16)wm[k * 4 + n];
    else if (n < 8) v = (_Float16)wl[k * 4 + (n - 4)];
    ws[PWH_OFF + t] = v;
  }
}

// R1-R6 rule: arch-VGPR live set <= ~200 or the allocator spills to scratch
// (>150 MB round-trip = entire runtime). TB=32/m2 halves accumulators
// (agg2 16 + u2 16 + acc 32 packed/f32) -> ~120-160 live -> 3-4 waves/SIMD
// for L2-latency hiding. Keep R5's barrier structure (known-good), drop the
// per-perm build phases (obj tiles prebuilt; one-hot folded into bias; base
// contribution U precomputed so per-perm GEMM1 is K=32).
__global__ __launch_bounds__(256) void actor_fused(
    const float* __restrict__ obs, const float* __restrict__ lemb,
    const float* __restrict__ w1, const _Float16* __restrict__ ws,
    const float* __restrict__ b1, const float* __restrict__ b2,
    const float* __restrict__ br, const float* __restrict__ bm,
    const float* __restrict__ bl, float* __restrict__ out)
{
  __shared__ __align__(16) _Float16 Hs[TB * 256];      // 16 KB: base / h1 / agg / r
  __shared__ __align__(16) _Float16 Os[6 * TB * 32];   // 12 KB: 6 obj feature tiles

  const _Float16* __restrict__ pw1b = ws + PW1B_OFF;
  const _Float16* __restrict__ pw1f = ws + PW1F_OFF;
  const _Float16* __restrict__ pw2  = ws + PW2_OFF;
  const _Float16* __restrict__ pwr  = ws + PWR_OFF;
  const _Float16* __restrict__ pwh  = ws + PWH_OFF;

  const int tid  = threadIdx.x;
  const int wave = tid >> 6;
  const int lane = tid & 63;
  const int q    = lane >> 4;
  const int l16  = lane & 15;
  const int colbase = wave * 64;
  const int rowbase = blockIdx.x * TB;

  // ---- stage base (K=128: lemb 100 + body 10 + pad) into Hs ktc 0..3 ----
  for (int idx = tid; idx < TB * 128; idx += 256) {
    int r = idx >> 7, c = idx & 127;
    float v = 0.f;
    if (c < 100)      v = lemb[(rowbase + r) * 100 + c];
    else if (c < 110) v = obs[(rowbase + r) * 55 + (c - 100)];
    Hs[HIDX(r, c)] = (_Float16)v;
  }
  // ---- stage 6 obj tiles (32 rows x 32 cols: feat_i 15 | feat_j 15 | pad) ----
  for (int idx = tid; idx < 6 * TB * 32; idx += 256) {
    int p = idx >> 10, rem = idx & 1023, r = rem >> 5, c = rem & 31;
    int oi = p >> 1, oj = (1161 >> (2 * p)) & 3;
    float v = 0.f;
    if (c < 15)      v = obs[(rowbase + r) * 55 + 10 + oi * 15 + c];
    else if (c < 30) v = obs[(rowbase + r) * 55 + 10 + oj * 15 + (c - 15)];
    Os[p * 1024 + ((c >> 3) * 32 + r) * 8 + (c & 7)] = (_Float16)v;
  }
  __syncthreads();

  const fx4 zero4 = {0.f, 0.f, 0.f, 0.f};

  // ---- U = base @ W1base (K=128), this wave's 64 cols, packed f16 (16 regs) ----
  half2v u2[16];
  {
    fx4 acc[8];
    #pragma unroll
    for (int i = 0; i < 8; ++i) acc[i] = zero4;
    #pragma unroll 2
    for (int kt = 0; kt < 4; ++kt) {
      half8 a[2];
      #pragma unroll
      for (int m = 0; m < 2; ++m)
        a[m] = *(const half8*)&Hs[((kt * 4 + q) * 32 + m * 16 + l16) * 8];
      #pragma unroll
      for (int nt = 0; nt < 4; ++nt) {
        half8 b = *(const half8*)&pw1b[(kt * 256 + colbase + nt * 16 + l16) * 32 + q * 8];
        #pragma unroll
        for (int m = 0; m < 2; ++m)
          acc[m * 4 + nt] = __builtin_amdgcn_mfma_f32_16x16x32_f16(a[m], b, acc[m * 4 + nt], 0, 0, 0);
      }
    }
    #pragma unroll
    for (int i = 0; i < 8; ++i)
      #pragma unroll
      for (int rp = 0; rp < 2; ++rp) {
        half2v hv;
        hv[0] = (_Float16)acc[i][rp * 2 + 0];
        hv[1] = (_Float16)acc[i][rp * 2 + 1];
        u2[i * 2 + rp] = hv;
      }
  }
  __syncthreads();  // all waves done reading base from Hs before GEMM1 writes

  half2v agg2[16];
  #pragma unroll
  for (int i = 0; i < 16; ++i) agg2[i] = (half2v)0;

  for (int p = 0; p < 6; ++p) {
    const int oi = p >> 1;
    const int oj = (1161 >> (2 * p)) & 3; // IDX_J = {1,2,0,2,0,1}
    const float* __restrict__ w1i = w1 + (110 + oi) * 256;  // one-hot i fold
    const float* __restrict__ w1j = w1 + (128 + oj) * 256;  // one-hot j fold

    // ---- GEMM1: h1 = relu(U + F_p @ W1f + bias_p), K=32 ----
    {
      half8 af[2];
      #pragma unroll
      for (int m = 0; m < 2; ++m)
        af[m] = *(const half8*)&Os[p * 1024 + (q * 32 + m * 16 + l16) * 8];
      #pragma unroll
      for (int nt = 0; nt < 4; ++nt) {
        half8 b = *(const half8*)&pw1f[(colbase + nt * 16 + l16) * 32 + q * 8];
        int col = colbase + nt * 16 + l16;
        float bs = b1[col] + w1i[col] + w1j[col];
        #pragma unroll
        for (int m = 0; m < 2; ++m) {
          fx4 acc;
          int s = (m * 4 + nt) * 2;
          acc[0] = (float)u2[s][0];     acc[1] = (float)u2[s][1];
          acc[2] = (float)u2[s + 1][0]; acc[3] = (float)u2[s + 1][1];
          acc = __builtin_amdgcn_mfma_f32_16x16x32_f16(af[m], b, acc, 0, 0, 0);
          #pragma unroll
          for (int rr = 0; rr < 4; ++rr) {
            float h = acc[rr] + bs;
            Hs[HIDX(m * 16 + q * 4 + rr, col)] = (_Float16)(h > 0.f ? h : 0.f);
          }
        }
      }
    }
    __syncthreads();

    // ---- GEMM2: agg += relu(h1 @ W2 + b2), K=256 ----
    {
      fx4 acc[8];
      #pragma unroll
      for (int i = 0; i < 8; ++i) acc[i] = zero4;
      #pragma unroll 2
      for (int kt = 0; kt < 8; ++kt) {
        half8 a[2];
        #pragma unroll
        for (int m = 0; m < 2; ++m)
          a[m] = *(const half8*)&Hs[((kt * 4 + q) * 32 + m * 16 + l16) * 8];
        #pragma unroll
        for (int nt = 0; nt < 4; ++nt) {
          half8 b = *(const half8*)&pw2[(kt * 256 + colbase + nt * 16 + l16) * 32 + q * 8];
          #pragma unroll
          for (int m = 0; m < 2; ++m)
            acc[m * 4 + nt] = __builtin_amdgcn_mfma_f32_16x16x32_f16(a[m], b, acc[m * 4 + nt], 0, 0, 0);
        }
      }
      #pragma unroll
      for (int i = 0; i < 8; ++i) {
        int nt = i & 3;
        float bs = b2[colbase + nt * 16 + l16];
        #pragma unroll
        for (int rp = 0; rp < 2; ++rp) {
          float h0 = acc[i][rp * 2 + 0] + bs;
          float h1 = acc[i][rp * 2 + 1] + bs;
          half2v hv;
          hv[0] = (_Float16)(h0 > 0.f ? h0 : 0.f);
          hv[1] = (_Float16)(h1 > 0.f ? h1 : 0.f);
          agg2[i * 2 + rp] += hv;   // v_pk_add_f16
        }
      }
    }
    __syncthreads();  // Hs reads done before next perm's GEMM1 writes
  }

  // ---- stage agg2 -> Hs (f16) ----
  #pragma unroll
  for (int i = 0; i < 8; ++i) {
    int m = i >> 2, nt = i & 3;
    int col = colbase + nt * 16 + l16;
    #pragma unroll
    for (int rr = 0; rr < 4; ++rr)
      Hs[HIDX(m * 16 + q * 4 + rr, col)] = agg2[i * 2 + (rr >> 1)][rr & 1];
  }
  __syncthreads();

  // ---- GEMM3: r = relu(agg @ rho + br), K=256 ----
  {
    fx4 acc3[8];
    #pragma unroll
    for (int i = 0; i < 8; ++i) acc3[i] = zero4;
    #pragma unroll 2
    for (int kt = 0; kt < 8; ++kt) {
      half8 a[2];
      #pragma unroll
      for (int m = 0; m < 2; ++m)
        a[m] = *(const half8*)&Hs[((kt * 4 + q) * 32 + m * 16 + l16) * 8];
      #pragma unroll
      for (int nt = 0; nt < 4; ++nt) {
        half8 b = *(const half8*)&pwr[(kt * 256 + colbase + nt * 16 + l16) * 32 + q * 8];
        #pragma unroll
        for (int m = 0; m < 2; ++m)
          acc3[m * 4 + nt] = __builtin_amdgcn_mfma_f32_16x16x32_f16(a[m], b, acc3[m * 4 + nt], 0, 0, 0);
      }
    }
    __syncthreads();  // all reads of Hs done before overwrite
    #pragma unroll
    for (int i = 0; i < 8; ++i) {
      int m = i >> 2, nt = i & 3;
      int col = colbase + nt * 16 + l16;
      float bs = br[col];
      #pragma unroll
      for (int rr = 0; rr < 4; ++rr) {
        float h = acc3[i][rr] + bs;
        Hs[HIDX(m * 16 + q * 4 + rr, col)] = (_Float16)(h > 0.f ? h : 0.f);
      }
    }
  }
  __syncthreads();

  // ---- heads: waves 0,1 each handle 16 rows; [mean | log_std] = r @ PWh ----
  if (wave < 2) {
    fx4 a4 = zero4;
    for (int kt = 0; kt < 8; ++kt) {
      half8 a = *(const half8*)&Hs[((kt * 4 + q) * 32 + wave * 16 + l16) * 8];
      half8 b = *(const half8*)&pwh[(kt * 16 + l16) * 32 + q * 8];
      a4 = __builtin_amdgcn_mfma_f32_16x16x32_f16(a, b, a4, 0, 0, 0);
    }
    int gr = rowbase + wave * 16 + q * 4;
    if (l16 < 4) {
      float bias = bm[l16];
      #pragma unroll
      for (int rr = 0; rr < 4; ++rr) out[(gr + rr) * 4 + l16] = a4[rr] + bias;
    } else if (l16 < 8) {
      int c = l16 - 4;
      float bias = bl[c];
      #pragma unroll
      for (int rr = 0; rr < 4; ++rr) {
        float v = a4[rr] + bias;
        v = v < -20.f ? -20.f : (v > 2.f ? 2.f : v);
        out[BATCH * 4 + (gr + rr) * 4 + c] = v;
      }
    }
  }
}

extern "C" void kernel_launch(void* const* d_in, const int* in_sizes, int n_in,
                              void* d_out, int out_size, void* d_ws, size_t ws_size,
                              hipStream_t stream) {
  const float* obs  = (const float*)d_in[0];
  const float* lemb = (const float*)d_in[1];
  const float* w1   = (const float*)d_in[2];
  const float* b1   = (const float*)d_in[3];
  const float* w2   = (const float*)d_in[4];
  const float* b2   = (const float*)d_in[5];
  const float* wr   = (const float*)d_in[6];
  const float* br   = (const float*)d_in[7];
  const float* wm   = (const float*)d_in[8];
  const float* bm   = (const float*)d_in[9];
  const float* wl   = (const float*)d_in[10];
  const float* bl   = (const float*)d_in[11];
  float* out = (float*)d_out;
  _Float16* ws = (_Float16*)d_ws;

  hipLaunchKernelGGL(prep_weights, dim3(WS_TOTAL / 256), dim3(256), 0, stream,
                     w1, w2, wr, wm, wl, ws);
  hipLaunchKernelGGL(actor_fused, dim3(BATCH / TB), dim3(256), 0, stream,
                     obs, lemb, w1, (const _Float16*)ws, b1, b2, br, bm, bl, out);
}

// Round 8
// 215.464 us; speedup vs baseline: 4.7181x; 1.4001x over previous
//
#include <hip/hip_runtime.h>

#define BATCH 65536
#define TB 16

typedef _Float16 half8 __attribute__((ext_vector_type(8)));
typedef float fx4 __attribute__((ext_vector_type(4)));

// workspace layout (halves)
#define PW1B_OFF 0        // [4][256][32]  W1 base rows (k<110, pad->128)
#define PW1F_OFF 32768    // [256][32]     W1 feat rows: kk<15 -> feat_i (113+kk), kk 15..29 -> feat_j (131+kk-15)
#define PW2_OFF  40960    // [8][256][32]
#define PWR_OFF  106496   // [8][256][32]
#define PWH_OFF  172032   // [8][16][32]   [mean_w | lstd_w | pad]
#define WS_TOTAL 176128

// A-layout index for a 16-row x 256-col tile, fragment-major:
// a-frag read for (kt,q,l16) at ((kt*4+q)*16+l16)*8 is lane-contiguous 16B -> conflict-free b128.
#define HIDX(row, col) (((((col) >> 5) * 4 + (((col) >> 3) & 3)) * 16 + (row)) * 8 + ((col) & 7))

__global__ __launch_bounds__(256) void prep_weights(
    const float* __restrict__ w1, const float* __restrict__ w2,
    const float* __restrict__ wr, const float* __restrict__ wm,
    const float* __restrict__ wl, _Float16* __restrict__ ws)
{
  int idx = blockIdx.x * 256 + threadIdx.x;
  if (idx < 32768) {            // pw1b
    int kk = idx & 31, n = (idx >> 5) & 255, kt = idx >> 13;
    int k = kt * 32 + kk;
    ws[idx] = (k < 110) ? (_Float16)w1[k * 256 + n] : (_Float16)0.f;
  } else if (idx < 40960) {     // pw1f
    int t = idx - 32768;
    int kk = t & 31, n = t >> 5;
    _Float16 v = (_Float16)0.f;
    if (kk < 15)      v = (_Float16)w1[(113 + kk) * 256 + n];
    else if (kk < 30) v = (_Float16)w1[(131 + (kk - 15)) * 256 + n];
    ws[idx] = v;
  } else if (idx < 106496) {    // pw2
    int t = idx - 40960;
    int kk = t & 31, n = (t >> 5) & 255, kt = t >> 13;
    ws[idx] = (_Float16)w2[(kt * 32 + kk) * 256 + n];
  } else if (idx < 172032) {    // pwr
    int t = idx - 106496;
    int kk = t & 31, n = (t >> 5) & 255, kt = t >> 13;
    ws[idx] = (_Float16)wr[(kt * 32 + kk) * 256 + n];
  } else if (idx < WS_TOTAL) {  // pwh
    int t = idx - 172032;
    int kk = t & 31, n = (t >> 5) & 15, kt = t >> 9;
    int k = kt * 32 + kk;
    _Float16 v = (_Float16)0.f;
    if (n < 4) v = (_Float16)wm[k * 4 + n];
    else if (n < 8) v = (_Float16)wl[k * 4 + (n - 4)];
    ws[PWH_OFF + t] = v;
  }
}

// R7 post-mortem: dur invariant at ~235us across memory-traffic regimes ->
// limiter is the 17-barrier phase chain (2 drains/perm around tiny phases).
// R8: stack the 6 perms into one M=96 GEMM pair. GEMM1-all (K=32) and
// GEMM2-all (K=256, 96 MFMAs) each run as ONE phase; relu+sum of the 6
// row-groups happens in registers. 4 barriers total. 512 thr, wave owns 32
// N-cols; TB=16 rows/block. Live set ~110 regs (acc 48 AGPR) -> no spill,
// no __launch_bounds__ min-waves clamp (R2/R4 pathology).
__global__ __launch_bounds__(512) void actor_fused(
    const float* __restrict__ obs, const float* __restrict__ lemb,
    const float* __restrict__ w1, const _Float16* __restrict__ ws,
    const float* __restrict__ b1, const float* __restrict__ b2,
    const float* __restrict__ br, const float* __restrict__ bm,
    const float* __restrict__ bl, float* __restrict__ out)
{
  __shared__ __align__(16) _Float16 Rs[16 * 256];     //  8 KB: base (K=128) then agg
  __shared__ __align__(16) _Float16 H1[6 * 16 * 256]; // 48 KB: h1_all; r reuses H1[0..4095]
  __shared__ __align__(16) _Float16 Os[6 * 16 * 32];  //  6 KB: obj feature tiles

  const _Float16* __restrict__ pw1b = ws + PW1B_OFF;
  const _Float16* __restrict__ pw1f = ws + PW1F_OFF;
  const _Float16* __restrict__ pw2  = ws + PW2_OFF;
  const _Float16* __restrict__ pwr  = ws + PWR_OFF;
  const _Float16* __restrict__ pwh  = ws + PWH_OFF;

  const int tid  = threadIdx.x;
  const int wave = tid >> 6;        // 0..7
  const int lane = tid & 63;
  const int q    = lane >> 4;
  const int l16  = lane & 15;
  const int colbase = wave * 32;    // this wave's 32 output cols
  const int rowbase = blockIdx.x * TB;

  // ---- stage base (16 rows x K=128: lemb 100 + body 10 + pad) ----
  for (int idx = tid; idx < 2048; idx += 512) {
    int r = idx >> 7, c = idx & 127;
    float v = 0.f;
    if (c < 100)      v = lemb[(rowbase + r) * 100 + c];
    else if (c < 110) v = obs[(rowbase + r) * 55 + (c - 100)];
    Rs[HIDX(r, c)] = (_Float16)v;
  }
  // ---- stage 6 obj tiles (16 x 32: feat_i 15 | feat_j 15 | pad) ----
  for (int idx = tid; idx < 3072; idx += 512) {
    int p = idx >> 9, rem = idx & 511, r = rem >> 5, c = rem & 31;
    int oi = p >> 1, oj = (1161 >> (2 * p)) & 3;
    float v = 0.f;
    if (c < 15)      v = obs[(rowbase + r) * 55 + 10 + oi * 15 + c];
    else if (c < 30) v = obs[(rowbase + r) * 55 + 10 + oj * 15 + (c - 15)];
    Os[p * 512 + ((c >> 3) * 16 + r) * 8 + (c & 7)] = (_Float16)v;
  }
  __syncthreads();

  const fx4 zero4 = {0.f, 0.f, 0.f, 0.f};

  // ---- U = base @ W1base (K=128), M=16, this wave's 32 cols ----
  fx4 u[2];
  u[0] = zero4; u[1] = zero4;
  #pragma unroll 2
  for (int kt = 0; kt < 4; ++kt) {
    half8 a = *(const half8*)&Rs[((kt * 4 + q) * 16 + l16) * 8];
    #pragma unroll
    for (int nt = 0; nt < 2; ++nt) {
      half8 b = *(const half8*)&pw1b[(kt * 256 + colbase + nt * 16 + l16) * 32 + q * 8];
      u[nt] = __builtin_amdgcn_mfma_f32_16x16x32_f16(a, b, u[nt], 0, 0, 0);
    }
  }

  // ---- GEMM1-all: h1_p = relu(U + F_p @ W1f + bias_p), p=0..5, K=32, one phase ----
  #pragma unroll
  for (int p = 0; p < 6; ++p) {
    const int oi = p >> 1;
    const int oj = (1161 >> (2 * p)) & 3;
    const float* __restrict__ w1i = w1 + (110 + oi) * 256;  // one-hot i fold (f32)
    const float* __restrict__ w1j = w1 + (128 + oj) * 256;  // one-hot j fold
    half8 af = *(const half8*)&Os[p * 512 + (q * 16 + l16) * 8];
    #pragma unroll
    for (int nt = 0; nt < 2; ++nt) {
      int col = colbase + nt * 16 + l16;
      half8 b = *(const half8*)&pw1f[col * 32 + q * 8];
      fx4 acc = u[nt];
      acc = __builtin_amdgcn_mfma_f32_16x16x32_f16(af, b, acc, 0, 0, 0);
      float bs = b1[col] + w1i[col] + w1j[col];
      #pragma unroll
      for (int rr = 0; rr < 4; ++rr) {
        float h = acc[rr] + bs;
        H1[p * 4096 + HIDX(q * 4 + rr, col)] = (_Float16)(h > 0.f ? h : 0.f);
      }
    }
  }
  __syncthreads();

  // ---- GEMM2-all: M=96 (6 perms x 16 rows), K=256, one long phase ----
  fx4 acc[12];
  #pragma unroll
  for (int i = 0; i < 12; ++i) acc[i] = zero4;
  #pragma unroll 2
  for (int kt = 0; kt < 8; ++kt) {
    half8 a[6];
    #pragma unroll
    for (int p = 0; p < 6; ++p)
      a[p] = *(const half8*)&H1[p * 4096 + ((kt * 4 + q) * 16 + l16) * 8];
    #pragma unroll
    for (int nt = 0; nt < 2; ++nt) {
      half8 b = *(const half8*)&pw2[(kt * 256 + colbase + nt * 16 + l16) * 32 + q * 8];
      #pragma unroll
      for (int p = 0; p < 6; ++p)
        acc[p * 2 + nt] = __builtin_amdgcn_mfma_f32_16x16x32_f16(a[p], b, acc[p * 2 + nt], 0, 0, 0);
    }
  }
  // relu + sum the 6 row-groups in registers -> agg (16 rows x 32 cols/wave)
  fx4 agg[2];
  agg[0] = zero4; agg[1] = zero4;
  #pragma unroll
  for (int nt = 0; nt < 2; ++nt) {
    float bs = b2[colbase + nt * 16 + l16];
    #pragma unroll
    for (int p = 0; p < 6; ++p)
      #pragma unroll
      for (int rr = 0; rr < 4; ++rr) {
        float h = acc[p * 2 + nt][rr] + bs;
        if (h > 0.f) agg[nt][rr] += h;
      }
  }
  // stage agg -> Rs (base region dead since U; all waves past barrier 2)
  #pragma unroll
  for (int nt = 0; nt < 2; ++nt) {
    int col = colbase + nt * 16 + l16;
    #pragma unroll
    for (int rr = 0; rr < 4; ++rr)
      Rs[HIDX(q * 4 + rr, col)] = (_Float16)agg[nt][rr];
  }
  __syncthreads();

  // ---- GEMM3: r = relu(agg @ rho + br), M=16, K=256 ----
  fx4 acc3[2];
  acc3[0] = zero4; acc3[1] = zero4;
  #pragma unroll 2
  for (int kt = 0; kt < 8; ++kt) {
    half8 a = *(const half8*)&Rs[((kt * 4 + q) * 16 + l16) * 8];
    #pragma unroll
    for (int nt = 0; nt < 2; ++nt) {
      half8 b = *(const half8*)&pwr[(kt * 256 + colbase + nt * 16 + l16) * 32 + q * 8];
      acc3[nt] = __builtin_amdgcn_mfma_f32_16x16x32_f16(a, b, acc3[nt], 0, 0, 0);
    }
  }
  // write r into H1[0..4095] (H1 reads all finished before previous barrier)
  #pragma unroll
  for (int nt = 0; nt < 2; ++nt) {
    int col = colbase + nt * 16 + l16;
    float bs = br[col];
    #pragma unroll
    for (int rr = 0; rr < 4; ++rr) {
      float h = acc3[nt][rr] + bs;
      H1[HIDX(q * 4 + rr, col)] = (_Float16)(h > 0.f ? h : 0.f);
    }
  }
  __syncthreads();

  // ---- heads: wave 0 computes [mean | log_std] = r @ PWh (N padded 16) ----
  if (wave == 0) {
    fx4 a4 = zero4;
    for (int kt = 0; kt < 8; ++kt) {
      half8 a = *(const half8*)&H1[((kt * 4 + q) * 16 + l16) * 8];
      half8 b = *(const half8*)&pwh[(kt * 16 + l16) * 32 + q * 8];
      a4 = __builtin_amdgcn_mfma_f32_16x16x32_f16(a, b, a4, 0, 0, 0);
    }
    int gr = rowbase + q * 4;
    if (l16 < 4) {
      float bias = bm[l16];
      #pragma unroll
      for (int rr = 0; rr < 4; ++rr) out[(gr + rr) * 4 + l16] = a4[rr] + bias;
    } else if (l16 < 8) {
      int c = l16 - 4;
      float bias = bl[c];
      #pragma unroll
      for (int rr = 0; rr < 4; ++rr) {
        float v = a4[rr] + bias;
        v = v < -20.f ? -20.f : (v > 2.f ? 2.f : v);
        out[BATCH * 4 + (gr + rr) * 4 + c] = v;
      }
    }
  }
}

extern "C" void kernel_launch(void* const* d_in, const int* in_sizes, int n_in,
                              void* d_out, int out_size, void* d_ws, size_t ws_size,
                              hipStream_t stream) {
  const float* obs  = (const float*)d_in[0];
  const float* lemb = (const float*)d_in[1];
  const float* w1   = (const float*)d_in[2];
  const float* b1   = (const float*)d_in[3];
  const float* w2   = (const float*)d_in[4];
  const float* b2   = (const float*)d_in[5];
  const float* wr   = (const float*)d_in[6];
  const float* br   = (const float*)d_in[7];
  const float* wm   = (const float*)d_in[8];
  const float* bm   = (const float*)d_in[9];
  const float* wl   = (const float*)d_in[10];
  const float* bl   = (const float*)d_in[11];
  float* out = (float*)d_out;
  _Float16* ws = (_Float16*)d_ws;

  hipLaunchKernelGGL(prep_weights, dim3(WS_TOTAL / 256), dim3(256), 0, stream,
                     w1, w2, wr, wm, wl, ws);
  hipLaunchKernelGGL(actor_fused, dim3(BATCH / TB), dim3(512), 0, stream,
                     obs, lemb, w1, (const _Float16*)ws, b1, b2, br, bm, bl, out);
}

// Round 9
// 209.034 us; speedup vs baseline: 4.8633x; 1.0308x over previous
//
#include <hip/hip_runtime.h>

#define BATCH 65536
#define TB 16

typedef _Float16 half8 __attribute__((ext_vector_type(8)));
typedef float fx4 __attribute__((ext_vector_type(4)));

// workspace layout (halves)
#define PW1B_OFF 0        // [4][256][32]  W1 base rows (k<110, pad->128)
#define PW1F_OFF 32768    // [256][32]     W1 feat rows, k-map [feat_i(15) 0 feat_j(15) 0]
#define PW2_OFF  40960    // [8][256][32]
#define PWR_OFF  106496   // [8][256][32]
#define PWH_OFF  172032   // [8][16][32]   [mean_w | lstd_w | pad]
#define WS_TOTAL 176128

// A-layout index for a 16-row x 256-col tile, fragment-major:
// a-frag read for (kt,q,l16) at ((kt*4+q)*16+l16)*8 -> uniform-bank b128.
#define HIDX(row, col) (((((col) >> 5) * 4 + (((col) >> 3) & 3)) * 16 + (row)) * 8 + ((col) & 7))

__global__ __launch_bounds__(256) void prep_weights(
    const float* __restrict__ w1, const float* __restrict__ w2,
    const float* __restrict__ wr, const float* __restrict__ wm,
    const float* __restrict__ wl, _Float16* __restrict__ ws)
{
  int idx = blockIdx.x * 256 + threadIdx.x;
  if (idx < 32768) {            // pw1b
    int kk = idx & 31, n = (idx >> 5) & 255, kt = idx >> 13;
    int k = kt * 32 + kk;
    ws[idx] = (k < 110) ? (_Float16)w1[k * 256 + n] : (_Float16)0.f;
  } else if (idx < 40960) {     // pw1f: kk 0-14 feat_i rows 113+, kk 16-30 feat_j rows 131+
    int t = idx - 32768;
    int kk = t & 31, n = t >> 5;
    _Float16 v = (_Float16)0.f;
    if (kk < 15)                  v = (_Float16)w1[(113 + kk) * 256 + n];
    else if (kk >= 16 && kk < 31) v = (_Float16)w1[(131 + (kk - 16)) * 256 + n];
    ws[idx] = v;
  } else if (idx < 106496) {    // pw2
    int t = idx - 40960;
    int kk = t & 31, n = (t >> 5) & 255, kt = t >> 13;
    ws[idx] = (_Float16)w2[(kt * 32 + kk) * 256 + n];
  } else if (idx < 172032) {    // pwr
    int t = idx - 106496;
    int kk = t & 31, n = (t >> 5) & 255, kt = t >> 13;
    ws[idx] = (_Float16)wr[(kt * 32 + kk) * 256 + n];
  } else if (idx < WS_TOTAL) {  // pwh
    int t = idx - 172032;
    int kk = t & 31, n = (t >> 5) & 15, kt = t >> 9;
    int k = kt * 32 + kk;
    _Float16 v = (_Float16)0.f;
    if (n < 4) v = (_Float16)wm[k * 4 + n];
    else if (n < 8) v = (_Float16)wl[k * 4 + (n - 4)];
    ws[PWH_OFF + t] = v;
  }
}

// R8 post-mortem: 3 co-limiters ~35-40us each (MFMA, LDS reads, L2 weight BW)
// at 41% occupancy (LDS 62KB -> 2 blk/CU). R9: LDS cut to 52.5KB -> 3 blk/CU:
// compact obj tiles (3 unique objects, quad-addressed A-frags), base staged in
// H1 scratch, fused per-perm biases precomputed into LDS (kills 18 L2 loads
// per wave in GEMM1 epilogue). Same math as R8 (verified absmax 0.031).
__global__ __launch_bounds__(512) void actor_fused(
    const float* __restrict__ obs, const float* __restrict__ lemb,
    const float* __restrict__ w1, const _Float16* __restrict__ ws,
    const float* __restrict__ b1, const float* __restrict__ b2,
    const float* __restrict__ br, const float* __restrict__ bm,
    const float* __restrict__ bl, float* __restrict__ out)
{
  __shared__ __align__(16) _Float16 H1[6 * 16 * 256]; // 48 KB: base / h1_all / agg / r
  __shared__ __align__(16) _Float16 Os[3 * 16 * 16];  // 1.5 KB: compact obj tiles
  __shared__ __align__(16) _Float16 Bs[6 * 256];      // 3 KB: fused per-perm biases

  const _Float16* __restrict__ pw1b = ws + PW1B_OFF;
  const _Float16* __restrict__ pw1f = ws + PW1F_OFF;
  const _Float16* __restrict__ pw2  = ws + PW2_OFF;
  const _Float16* __restrict__ pwr  = ws + PWR_OFF;
  const _Float16* __restrict__ pwh  = ws + PWH_OFF;

  const int tid  = threadIdx.x;
  const int wave = tid >> 6;        // 0..7
  const int lane = tid & 63;
  const int q    = lane >> 4;
  const int l16  = lane & 15;
  const int colbase = wave * 32;    // this wave's 32 output cols
  const int rowbase = blockIdx.x * TB;

  // ---- stage base (16 rows x K=128) into H1[0:2048] ----
  for (int idx = tid; idx < 2048; idx += 512) {
    int r = idx >> 7, c = idx & 127;
    float v = 0.f;
    if (c < 100)      v = lemb[(rowbase + r) * 100 + c];
    else if (c < 110) v = obs[(rowbase + r) * 55 + (c - 100)];
    H1[HIDX(r, c)] = (_Float16)v;
  }
  // ---- compact obj tiles: 3 objects x 16 rows x 16 k (15 feats + pad) ----
  for (int idx = tid; idx < 768; idx += 512) {
    int o = idx >> 8, rem = idx & 255, r = rem >> 4, c = rem & 15;
    float v = (c < 15) ? obs[(rowbase + r) * 55 + 10 + o * 15 + c] : 0.f;
    Os[o * 256 + ((c >> 3) * 16 + r) * 8 + (c & 7)] = (_Float16)v;
  }
  // ---- fused per-perm biases: b1 + W1[onehot_i row] + W1[onehot_j row] ----
  for (int idx = tid; idx < 1536; idx += 512) {
    int p = idx >> 8, c = idx & 255;
    int oi = p >> 1, oj = (1161 >> (2 * p)) & 3;
    Bs[idx] = (_Float16)(b1[c] + w1[(110 + oi) * 256 + c] + w1[(128 + oj) * 256 + c]);
  }
  __syncthreads();

  const fx4 zero4 = {0.f, 0.f, 0.f, 0.f};

  // ---- U = base @ W1base (K=128), M=16, this wave's 32 cols ----
  fx4 u[2];
  u[0] = zero4; u[1] = zero4;
  #pragma unroll 2
  for (int kt = 0; kt < 4; ++kt) {
    half8 a = *(const half8*)&H1[((kt * 4 + q) * 16 + l16) * 8];
    #pragma unroll
    for (int nt = 0; nt < 2; ++nt) {
      half8 b = *(const half8*)&pw1b[(kt * 256 + colbase + nt * 16 + l16) * 32 + q * 8];
      u[nt] = __builtin_amdgcn_mfma_f32_16x16x32_f16(a, b, u[nt], 0, 0, 0);
    }
  }
  __syncthreads();  // base region of H1 dead; GEMM1 may overwrite

  // ---- GEMM1-all: h1_p = relu(U + F_p @ W1f + bias_p), p=0..5, K=32 ----
  // A k-map: quad 0,1 -> feat_i (k 0..15), quad 2,3 -> feat_j (k 16..31)
  #pragma unroll
  for (int p = 0; p < 6; ++p) {
    const int oi = p >> 1;
    const int oj = (1161 >> (2 * p)) & 3;
    const int o = (q < 2) ? oi : oj;
    half8 af = *(const half8*)&Os[o * 256 + ((q & 1) * 16 + l16) * 8];
    #pragma unroll
    for (int nt = 0; nt < 2; ++nt) {
      int col = colbase + nt * 16 + l16;
      half8 b = *(const half8*)&pw1f[col * 32 + q * 8];
      fx4 acc = u[nt];
      acc = __builtin_amdgcn_mfma_f32_16x16x32_f16(af, b, acc, 0, 0, 0);
      float bs = (float)Bs[p * 256 + col];
      #pragma unroll
      for (int rr = 0; rr < 4; ++rr) {
        float h = acc[rr] + bs;
        H1[p * 4096 + HIDX(q * 4 + rr, col)] = (_Float16)(h > 0.f ? h : 0.f);
      }
    }
  }
  __syncthreads();

  // ---- GEMM2-all: M=96 (6 perms x 16 rows), K=256, one long phase ----
  fx4 acc[12];
  #pragma unroll
  for (int i = 0; i < 12; ++i) acc[i] = zero4;
  #pragma unroll 2
  for (int kt = 0; kt < 8; ++kt) {
    half8 a[6];
    #pragma unroll
    for (int p = 0; p < 6; ++p)
      a[p] = *(const half8*)&H1[p * 4096 + ((kt * 4 + q) * 16 + l16) * 8];
    #pragma unroll
    for (int nt = 0; nt < 2; ++nt) {
      half8 b = *(const half8*)&pw2[(kt * 256 + colbase + nt * 16 + l16) * 32 + q * 8];
      #pragma unroll
      for (int p = 0; p < 6; ++p)
        acc[p * 2 + nt] = __builtin_amdgcn_mfma_f32_16x16x32_f16(a[p], b, acc[p * 2 + nt], 0, 0, 0);
    }
  }
  // relu + sum the 6 row-groups in registers -> agg (16 rows x 32 cols/wave)
  fx4 agg[2];
  agg[0] = zero4; agg[1] = zero4;
  #pragma unroll
  for (int nt = 0; nt < 2; ++nt) {
    float bs = b2[colbase + nt * 16 + l16];
    #pragma unroll
    for (int p = 0; p < 6; ++p)
      #pragma unroll
      for (int rr = 0; rr < 4; ++rr) {
        float h = acc[p * 2 + nt][rr] + bs;
        if (h > 0.f) agg[nt][rr] += h;
      }
  }
  __syncthreads();  // all waves done reading H1 before agg overwrites region 0

  // stage agg -> H1[0:2048]
  #pragma unroll
  for (int nt = 0; nt < 2; ++nt) {
    int col = colbase + nt * 16 + l16;
    #pragma unroll
    for (int rr = 0; rr < 4; ++rr)
      H1[HIDX(q * 4 + rr, col)] = (_Float16)agg[nt][rr];
  }
  __syncthreads();

  // ---- GEMM3: r = relu(agg @ rho + br), M=16, K=256; r -> H1[4096:8192] ----
  fx4 acc3[2];
  acc3[0] = zero4; acc3[1] = zero4;
  #pragma unroll 2
  for (int kt = 0; kt < 8; ++kt) {
    half8 a = *(const half8*)&H1[((kt * 4 + q) * 16 + l16) * 8];
    #pragma unroll
    for (int nt = 0; nt < 2; ++nt) {
      half8 b = *(const half8*)&pwr[(kt * 256 + colbase + nt * 16 + l16) * 32 + q * 8];
      acc3[nt] = __builtin_amdgcn_mfma_f32_16x16x32_f16(a, b, acc3[nt], 0, 0, 0);
    }
  }
  #pragma unroll
  for (int nt = 0; nt < 2; ++nt) {
    int col = colbase + nt * 16 + l16;
    float bs = br[col];
    #pragma unroll
    for (int rr = 0; rr < 4; ++rr) {
      float h = acc3[nt][rr] + bs;
      H1[4096 + HIDX(q * 4 + rr, col)] = (_Float16)(h > 0.f ? h : 0.f);
    }
  }
  __syncthreads();

  // ---- heads: wave 0 computes [mean | log_std] = r @ PWh (N padded 16) ----
  if (wave == 0) {
    fx4 a4 = zero4;
    for (int kt = 0; kt < 8; ++kt) {
      half8 a = *(const half8*)&H1[4096 + ((kt * 4 + q) * 16 + l16) * 8];
      half8 b = *(const half8*)&pwh[(kt * 16 + l16) * 32 + q * 8];
      a4 = __builtin_amdgcn_mfma_f32_16x16x32_f16(a, b, a4, 0, 0, 0);
    }
    int gr = rowbase + q * 4;
    if (l16 < 4) {
      float bias = bm[l16];
      #pragma unroll
      for (int rr = 0; rr < 4; ++rr) out[(gr + rr) * 4 + l16] = a4[rr] + bias;
    } else if (l16 < 8) {
      int c = l16 - 4;
      float bias = bl[c];
      #pragma unroll
      for (int rr = 0; rr < 4; ++rr) {
        float v = a4[rr] + bias;
        v = v < -20.f ? -20.f : (v > 2.f ? 2.f : v);
        out[BATCH * 4 + (gr + rr) * 4 + c] = v;
      }
    }
  }
}

extern "C" void kernel_launch(void* const* d_in, const int* in_sizes, int n_in,
                              void* d_out, int out_size, void* d_ws, size_t ws_size,
                              hipStream_t stream) {
  const float* obs  = (const float*)d_in[0];
  const float* lemb = (const float*)d_in[1];
  const float* w1   = (const float*)d_in[2];
  const float* b1   = (const float*)d_in[3];
  const float* w2   = (const float*)d_in[4];
  const float* b2   = (const float*)d_in[5];
  const float* wr   = (const float*)d_in[6];
  const float* br   = (const float*)d_in[7];
  const float* wm   = (const float*)d_in[8];
  const float* bm   = (const float*)d_in[9];
  const float* wl   = (const float*)d_in[10];
  const float* bl   = (const float*)d_in[11];
  float* out = (float*)d_out;
  _Float16* ws = (_Float16*)d_ws;

  hipLaunchKernelGGL(prep_weights, dim3(WS_TOTAL / 256), dim3(256), 0, stream,
                     w1, w2, wr, wm, wl, ws);
  hipLaunchKernelGGL(actor_fused, dim3(BATCH / TB), dim3(512), 0, stream,
                     obs, lemb, w1, (const _Float16*)ws, b1, b2, br, bm, bl, out);
}